// Round 2
// 498.101 us; speedup vs baseline: 1.0094x; 1.0094x over previous
//
#include <hip/hip_runtime.h>

// IRREPS = [(256,0),(128,1),(64,2),(32,3)]
// dim = 1184; float4 units: 296 per row
// f4 group boundaries: [0,64) g0, [64,160) g1, [160,240) g2, [240,296) g3
// per-iteration (f4 = lane + 64*it):
//   it=0: all g0 (scalars: mean-subtract + bias)
//   it=1: all g1
//   it=2: lane<32 -> g1, else g2
//   it=3: lane<48 -> g2, else g3
//   it=4: lanes 0..39 active, all g3

#define DIM   1184
#define NF4   296
#define EPSV  1e-5f
#define ROWS_PER_WAVE 8

typedef float f4 __attribute__((ext_vector_type(4)));   // clang vector: valid for nontemporal builtins

__device__ __forceinline__ float dot4(const f4 a) {
    return a.x*a.x + a.y*a.y + a.z*a.z + a.w*a.w;
}

__global__ __launch_bounds__(256) void eln_kernel(
    const float* __restrict__ x,
    const float* __restrict__ weight,
    const float* __restrict__ bias,
    float* __restrict__ out,
    int n_rows)
{
    const int wave    = threadIdx.x >> 6;
    const int lane    = threadIdx.x & 63;
    const int wave_id = blockIdx.x * 4 + wave;
    const int n_waves = gridDim.x * 4;

    // ---- row-invariant per-lane weight fragments (hoisted out of row loop) ----
    f4 w[5];
#pragma unroll
    for (int it = 0; it < 5; ++it) {
        const int f4i = lane + it * 64;
        float wt[4];
#pragma unroll
        for (int c = 0; c < 4; ++c) {
            const int e = f4i * 4 + c;
            int idx;
            if (e < 256)      idx = e;
            else if (e < 640) idx = 256 + (e - 256) / 3;
            else if (e < 960) idx = 384 + (e - 640) / 5;
            else              idx = 448 + (e - 960) / 7;
            idx = idx < 479 ? idx : 479;                 // clamp tail lanes in-bounds
            wt[c] = (f4i < NF4) ? weight[idx] : 0.f;
        }
        w[it].x = wt[0]; w[it].y = wt[1]; w[it].z = wt[2]; w[it].w = wt[3];
    }
    // bias covers exactly it=0 (elements 0..255), identity-mapped
    const f4 bb = ((const f4*)bias)[lane];

    for (int row = wave_id; row < n_rows; row += n_waves) {
        const f4* __restrict__ xr = (const f4*)(x + (size_t)row * DIM);
        f4* __restrict__ orow     = (f4*)(out + (size_t)row * DIM);

        // ---- streaming loads (nt: no cache allocate) ----
        const f4 v0 = __builtin_nontemporal_load(xr + lane);
        const f4 v1 = __builtin_nontemporal_load(xr + lane + 64);
        const f4 v2 = __builtin_nontemporal_load(xr + lane + 128);
        const f4 v3 = __builtin_nontemporal_load(xr + lane + 192);
        f4 v4 = (f4){0.f, 0.f, 0.f, 0.f};
        if (lane < 40) v4 = __builtin_nontemporal_load(xr + lane + 256);

        // ---- per-group partial sums (branch-free) ----
        float ssum = v0.x + v0.y + v0.z + v0.w;
        float sq0  = dot4(v0);
        const float s2_1 = dot4(v1);
        const float s2_2 = dot4(v2);
        const float s2_3 = dot4(v3);
        const float s2_4 = dot4(v4);            // zero for inactive lanes
        float sq1 = s2_1 + ((lane < 32) ? s2_2 : 0.f);
        float sq2 = ((lane < 32) ? 0.f : s2_2) + ((lane < 48) ? s2_3 : 0.f);
        float sq3 = ((lane < 48) ? 0.f : s2_3) + s2_4;

        // ---- 64-lane butterfly reduction ----
#pragma unroll
        for (int off = 32; off > 0; off >>= 1) {
            ssum += __shfl_xor(ssum, off);
            sq0  += __shfl_xor(sq0,  off);
            sq1  += __shfl_xor(sq1,  off);
            sq2  += __shfl_xor(sq2,  off);
            sq3  += __shfl_xor(sq3,  off);
        }

        const float m   = ssum * (1.f / 256.f);
        const float v0v = fmaxf(sq0 * (1.f / 256.f) - m * m, 0.f);
        const float rn0 = rsqrtf(v0v + EPSV);
        const float rn1 = rsqrtf(sq1 * (1.f / 384.f) + EPSV);
        const float rn2 = rsqrtf(sq2 * (1.f / 320.f) + EPSV);
        const float rn3 = rsqrtf(sq3 * (1.f / 224.f) + EPSV);
        const float rnA = (lane < 32) ? rn1 : rn2;   // it=2 select
        const float rnB = (lane < 48) ? rn2 : rn3;   // it=3 select

        // ---- branch-free scale + store (nt) ----
        f4 o;
        o.x = (v0.x - m) * (rn0 * w[0].x) + bb.x;
        o.y = (v0.y - m) * (rn0 * w[0].y) + bb.y;
        o.z = (v0.z - m) * (rn0 * w[0].z) + bb.z;
        o.w = (v0.w - m) * (rn0 * w[0].w) + bb.w;
        __builtin_nontemporal_store(o, orow + lane);

        o.x = v1.x * (rn1 * w[1].x);
        o.y = v1.y * (rn1 * w[1].y);
        o.z = v1.z * (rn1 * w[1].z);
        o.w = v1.w * (rn1 * w[1].w);
        __builtin_nontemporal_store(o, orow + lane + 64);

        o.x = v2.x * (rnA * w[2].x);
        o.y = v2.y * (rnA * w[2].y);
        o.z = v2.z * (rnA * w[2].z);
        o.w = v2.w * (rnA * w[2].w);
        __builtin_nontemporal_store(o, orow + lane + 128);

        o.x = v3.x * (rnB * w[3].x);
        o.y = v3.y * (rnB * w[3].y);
        o.z = v3.z * (rnB * w[3].z);
        o.w = v3.w * (rnB * w[3].w);
        __builtin_nontemporal_store(o, orow + lane + 192);

        if (lane < 40) {
            o.x = v4.x * (rn3 * w[4].x);
            o.y = v4.y * (rn3 * w[4].y);
            o.z = v4.z * (rn3 * w[4].z);
            o.w = v4.w * (rn3 * w[4].w);
            __builtin_nontemporal_store(o, orow + lane + 256);
        }
    }
}

extern "C" void kernel_launch(void* const* d_in, const int* in_sizes, int n_in,
                              void* d_out, int out_size, void* d_ws, size_t ws_size,
                              hipStream_t stream)
{
    const float* x      = (const float*)d_in[0];
    const float* weight = (const float*)d_in[1];
    const float* bias   = (const float*)d_in[2];
    float* out          = (float*)d_out;

    const int n_rows = in_sizes[0] / DIM;                          // 65536
    const int blocks = (n_rows + ROWS_PER_WAVE * 4 - 1) / (ROWS_PER_WAVE * 4);  // 2048
    eln_kernel<<<blocks, 256, 0, stream>>>(x, weight, bias, out, n_rows);
}

// Round 3
// 493.957 us; speedup vs baseline: 1.0179x; 1.0084x over previous
//
#include <hip/hip_runtime.h>

// IRREPS = [(256,0),(128,1),(64,2),(32,3)]
// dim = 1184; float4 units: 296 per row
// f4 group boundaries: [0,64) g0, [64,160) g1, [160,240) g2, [240,296) g3
// per-iteration (f4 = lane + 64*it):
//   it=0: all g0 (scalars: mean-subtract + bias)
//   it=1: all g1
//   it=2: lane<32 -> g1, else g2
//   it=3: lane<48 -> g2, else g3
//   it=4: lanes 0..39 active, all g3

#define DIM   1184
#define NF4   296
#define EPSV  1e-5f
#define ROWS_PER_WAVE 8

typedef float f4 __attribute__((ext_vector_type(4)));

__device__ __forceinline__ float dot4(const f4 a) {
    return a.x*a.x + a.y*a.y + a.z*a.z + a.w*a.w;
}

__global__ __launch_bounds__(256) void eln_kernel(
    const float* __restrict__ x,
    const float* __restrict__ weight,
    const float* __restrict__ bias,
    float* __restrict__ out,
    int n_rows)
{
    const int wave    = threadIdx.x >> 6;
    const int lane    = threadIdx.x & 63;
    const int wave_id = blockIdx.x * 4 + wave;
    const int n_waves = gridDim.x * 4;

    // ---- row-invariant per-lane weight fragments (hoisted out of row loop) ----
    f4 w[5];
#pragma unroll
    for (int it = 0; it < 5; ++it) {
        const int f4i = lane + it * 64;
        float wt[4];
#pragma unroll
        for (int c = 0; c < 4; ++c) {
            const int e = f4i * 4 + c;
            int idx;
            if (e < 256)      idx = e;
            else if (e < 640) idx = 256 + (e - 256) / 3;
            else if (e < 960) idx = 384 + (e - 640) / 5;
            else              idx = 448 + (e - 960) / 7;
            idx = idx < 479 ? idx : 479;                 // clamp tail lanes in-bounds
            wt[c] = (f4i < NF4) ? weight[idx] : 0.f;
        }
        w[it].x = wt[0]; w[it].y = wt[1]; w[it].z = wt[2]; w[it].w = wt[3];
    }
    const f4 bb = ((const f4*)bias)[lane];   // bias covers exactly it=0

    int row = wave_id;
    if (row >= n_rows) return;

    // ---- prologue: load first row ----
    const f4* __restrict__ xr = (const f4*)(x + (size_t)row * DIM);
    f4 v0 = __builtin_nontemporal_load(xr + lane);
    f4 v1 = __builtin_nontemporal_load(xr + lane + 64);
    f4 v2 = __builtin_nontemporal_load(xr + lane + 128);
    f4 v3 = __builtin_nontemporal_load(xr + lane + 192);
    f4 v4 = (f4){0.f, 0.f, 0.f, 0.f};
    if (lane < 40) v4 = __builtin_nontemporal_load(xr + lane + 256);

    while (true) {
        const int nrow = row + n_waves;
        const bool has_next = nrow < n_rows;   // wave-uniform (n_rows % n_waves == 0)

        // ---- prefetch next row BEFORE the reduction chain (keeps VMEM busy) ----
        f4 n0, n1, n2, n3, n4 = (f4){0.f, 0.f, 0.f, 0.f};
        if (has_next) {
            const f4* __restrict__ xn = (const f4*)(x + (size_t)nrow * DIM);
            n0 = __builtin_nontemporal_load(xn + lane);
            n1 = __builtin_nontemporal_load(xn + lane + 64);
            n2 = __builtin_nontemporal_load(xn + lane + 128);
            n3 = __builtin_nontemporal_load(xn + lane + 192);
            if (lane < 40) n4 = __builtin_nontemporal_load(xn + lane + 256);
        }

        // ---- per-group partial sums (branch-free) ----
        float ssum = v0.x + v0.y + v0.z + v0.w;
        float sq0  = dot4(v0);
        const float s2_1 = dot4(v1);
        const float s2_2 = dot4(v2);
        const float s2_3 = dot4(v3);
        const float s2_4 = dot4(v4);
        float sq1 = s2_1 + ((lane < 32) ? s2_2 : 0.f);
        float sq2 = ((lane < 32) ? 0.f : s2_2) + ((lane < 48) ? s2_3 : 0.f);
        float sq3 = ((lane < 48) ? 0.f : s2_3) + s2_4;

        // ---- 64-lane butterfly reduction ----
#pragma unroll
        for (int off = 32; off > 0; off >>= 1) {
            ssum += __shfl_xor(ssum, off);
            sq0  += __shfl_xor(sq0,  off);
            sq1  += __shfl_xor(sq1,  off);
            sq2  += __shfl_xor(sq2,  off);
            sq3  += __shfl_xor(sq3,  off);
        }

        const float m   = ssum * (1.f / 256.f);
        const float v0v = fmaxf(sq0 * (1.f / 256.f) - m * m, 0.f);
        const float rn0 = rsqrtf(v0v + EPSV);
        const float rn1 = rsqrtf(sq1 * (1.f / 384.f) + EPSV);
        const float rn2 = rsqrtf(sq2 * (1.f / 320.f) + EPSV);
        const float rn3 = rsqrtf(sq3 * (1.f / 224.f) + EPSV);
        const float rnA = (lane < 32) ? rn1 : rn2;   // it=2 select
        const float rnB = (lane < 48) ? rn2 : rn3;   // it=3 select

        // ---- branch-free scale + store (nt) ----
        f4* __restrict__ orow = (f4*)(out + (size_t)row * DIM);
        f4 o;
        o.x = (v0.x - m) * (rn0 * w[0].x) + bb.x;
        o.y = (v0.y - m) * (rn0 * w[0].y) + bb.y;
        o.z = (v0.z - m) * (rn0 * w[0].z) + bb.z;
        o.w = (v0.w - m) * (rn0 * w[0].w) + bb.w;
        __builtin_nontemporal_store(o, orow + lane);

        o.x = v1.x * (rn1 * w[1].x);
        o.y = v1.y * (rn1 * w[1].y);
        o.z = v1.z * (rn1 * w[1].z);
        o.w = v1.w * (rn1 * w[1].w);
        __builtin_nontemporal_store(o, orow + lane + 64);

        o.x = v2.x * (rnA * w[2].x);
        o.y = v2.y * (rnA * w[2].y);
        o.z = v2.z * (rnA * w[2].z);
        o.w = v2.w * (rnA * w[2].w);
        __builtin_nontemporal_store(o, orow + lane + 128);

        o.x = v3.x * (rnB * w[3].x);
        o.y = v3.y * (rnB * w[3].y);
        o.z = v3.z * (rnB * w[3].z);
        o.w = v3.w * (rnB * w[3].w);
        __builtin_nontemporal_store(o, orow + lane + 192);

        if (lane < 40) {
            o.x = v4.x * (rn3 * w[4].x);
            o.y = v4.y * (rn3 * w[4].y);
            o.z = v4.z * (rn3 * w[4].z);
            o.w = v4.w * (rn3 * w[4].w);
            __builtin_nontemporal_store(o, orow + lane + 256);
        }

        if (!has_next) break;
        row = nrow;
        v0 = n0; v1 = n1; v2 = n2; v3 = n3; v4 = n4;
    }
}

extern "C" void kernel_launch(void* const* d_in, const int* in_sizes, int n_in,
                              void* d_out, int out_size, void* d_ws, size_t ws_size,
                              hipStream_t stream)
{
    const float* x      = (const float*)d_in[0];
    const float* weight = (const float*)d_in[1];
    const float* bias   = (const float*)d_in[2];
    float* out          = (float*)d_out;

    const int n_rows = in_sizes[0] / DIM;                          // 65536
    const int blocks = (n_rows + ROWS_PER_WAVE * 4 - 1) / (ROWS_PER_WAVE * 4);  // 2048
    eln_kernel<<<blocks, 256, 0, stream>>>(x, weight, bias, out, n_rows);
}